// Round 3
// baseline (592.108 us; speedup 1.0000x reference)
//
#include <hip/hip_runtime.h>
#include <math.h>

// MPNN forward. Round 8:
//  - k_msg rewritten dst-CSR, ZERO atomics: was 5.1M scattered 4B atomicAdds
//    (occupancy 27->44% bought nothing => atomic drain suspected). Edges
//    counting-sorted by dst once (deg -> scan -> scatter); eh written in
//    sorted order; each block owns 64 dst nodes, segment-sums msg tiles in
//    registers via rowptr, writes agg4[ksplit] with coalesced float4 stores.
//    agg memsets removed (unconditional writes); GRU cnt from rowptr.
//    LDS exactly 32KB -> 5 blocks/CU -> all 157x8 blocks resident.
//  - Round 7: outs XOR-swizzle (kept verbatim in MFMA body).
//  - Round 6: k_set2set 256-thr node-parallel softmax, one-wave shfl scan.
//  - Rounds 1-5: K-split edge MFMA, fused GRU MFMA, split-bf16 hi/lo MFMA,
//    Bfat/Wg weight pre-pack.

#define Nn 10000
#define Ee 20000
#define Bb 400
#define KSTEPS 130   // 128 (q,d) steps + 2 bias steps (K = 4160)
#define S2S_CHUNK 1024

typedef __attribute__((ext_vector_type(8))) short bf16x8_t;
typedef __attribute__((ext_vector_type(4))) float f32x4_t;

__device__ __forceinline__ float sigmoidf_(float x) { return 1.f / (1.f + expf(-x)); }

// split 8 fp32 -> hi/lo bf16x8 fragments (validated round 4, absmax 0.0)
__device__ __forceinline__ void split8(const float* p, bf16x8_t& Ahi_, bf16x8_t& Alo_) {
    union { bf16x8_t v; unsigned u[4]; } hi, lo;
#pragma unroll
    for (int ii = 0; ii < 4; ++ii) {
        float pa = p[2 * ii], pb = p[2 * ii + 1];
        unsigned ua = __float_as_uint(pa), ub = __float_as_uint(pb);
        hi.u[ii] = (ua >> 16) | (ub & 0xFFFF0000u);
        float la = pa - __uint_as_float(ua & 0xFFFF0000u);
        float lb = pb - __uint_as_float(ub & 0xFFFF0000u);
        lo.u[ii] = (__float_as_uint(la) >> 16) | (__float_as_uint(lb) & 0xFFFF0000u);
    }
    Ahi_ = hi.v; Alo_ = lo.v;
}

__global__ __launch_bounds__(256) void k_in_linear(const float* __restrict__ x,
                                                   const float* __restrict__ Win,
                                                   const float* __restrict__ bin,
                                                   float* __restrict__ out) {
    int idx = blockIdx.x * 256 + threadIdx.x;
    if (idx >= Nn * 64) return;
    int n = idx >> 6, j = idx & 63;
    const float* xr = x + n * 32;
    const float* w = Win + j * 32;
    float acc = bin[j];
#pragma unroll
    for (int k = 0; k < 32; ++k) acc += xr[k] * w[k];
    out[idx] = fmaxf(acc, 0.f);
}

// edge MLP layer 1, writing rows in dst-sorted order (epos permutation).
__global__ __launch_bounds__(256) void k_edge_mlp1(const float* __restrict__ ea,
                                                   const float* __restrict__ W1,
                                                   const float* __restrict__ b1,
                                                   const int* __restrict__ epos,
                                                   float* __restrict__ eh) {
    int idx = blockIdx.x * 256 + threadIdx.x;
    if (idx >= Ee * 64) return;
    int e = idx >> 6, j = idx & 63;
    const float* ar = ea + e * 16;
    const float* w = W1 + j * 16;
    float acc = b1[j];
#pragma unroll
    for (int k = 0; k < 16; ++k) acc += ar[k] * w[k];
    eh[(size_t)epos[e] * 64 + j] = fmaxf(acc, 0.f);
}

// Bfat[kstep][h][nq][lane][i] (bf16), as round 4 (validated).
__global__ __launch_bounds__(256) void k_make_Bfat(const float* __restrict__ W2,
                                                   const float* __restrict__ b2,
                                                   unsigned short* __restrict__ Bfat) {
    int idx = blockIdx.x * 256 + threadIdx.x;
    if (idx >= KSTEPS * 4096) return;
    int i  = idx & 7;
    int l  = (idx >> 3) & 63;
    int nq = (idx >> 9) & 3;
    int h  = (idx >> 11) & 1;
    int ks = idx >> 12;
    int kap = ks * 32 + (l >> 4) * 8 + i;
    int f = nq * 16 + (l & 15);
    float w;
    if (kap < 4096) {
        int q = kap >> 6, d = kap & 63;
        w = W2[(size_t)(d * 64 + f) * 64 + q];
    } else {
        int d = kap - 4096;
        w = b2[d * 64 + f];
    }
    unsigned u = __float_as_uint(w);
    unsigned short outv;
    if (h == 0) {
        outv = (unsigned short)(u >> 16);
    } else {
        float lo = w - __uint_as_float(u & 0xFFFF0000u);
        outv = (unsigned short)(__float_as_uint(lo) >> 16);
    }
    Bfat[idx] = outv;
}

// Wg[ks][h][t][lane][i] (bf16): GRU-gates B table, N=256 cols.
__global__ __launch_bounds__(256) void k_make_Wg(const float* __restrict__ Wih,
                                                 const float* __restrict__ Whh,
                                                 unsigned short* __restrict__ Wg) {
    int idx = blockIdx.x * 256 + threadIdx.x;
    if (idx >= 4 * 2 * 16 * 64 * 8) return;
    int i  = idx & 7;
    int l  = (idx >> 3) & 63;
    int t  = (idx >> 9) & 15;
    int h  = (idx >> 13) & 1;
    int ks = idx >> 14;
    int k = ks * 32 + (l >> 4) * 8 + i;
    int u = t * 16 + (l & 15);
    int j = u & 63, part = u >> 6;   // 0:r, 1:z, 2:i_n, 3:h_n
    float w = 0.f;
    if (part == 0) w = (k < 64) ? Wih[(size_t)j * 64 + k]          : Whh[(size_t)j * 64 + (k - 64)];
    if (part == 1) w = (k < 64) ? Wih[(size_t)(64 + j) * 64 + k]   : Whh[(size_t)(64 + j) * 64 + (k - 64)];
    if (part == 2) w = (k < 64) ? Wih[(size_t)(128 + j) * 64 + k]  : 0.f;
    if (part == 3) w = (k < 64) ? 0.f : Whh[(size_t)(128 + j) * 64 + (k - 64)];
    unsigned uu = __float_as_uint(w);
    unsigned short outv;
    if (h == 0) {
        outv = (unsigned short)(uu >> 16);
    } else {
        float lo = w - __uint_as_float(uu & 0xFFFF0000u);
        outv = (unsigned short)(__float_as_uint(lo) >> 16);
    }
    Wg[idx] = outv;
}

__global__ __launch_bounds__(256) void k_count_deg(const int* __restrict__ ei,
                                                   int* __restrict__ deg) {
    int e = blockIdx.x * 256 + threadIdx.x;
    if (e >= Ee) return;
    atomicAdd(&deg[ei[Ee + e]], 1);
}

// Single-block exclusive scan of deg[Nn] -> rowptr[Nn+1], plus wptr copy.
__global__ __launch_bounds__(256) void k_scan_nodes(const int* __restrict__ deg,
                                                    int* __restrict__ rowptr,
                                                    int* __restrict__ wptr) {
    __shared__ int part[256];
    int t = threadIdx.x;
    const int PER = (Nn + 255) / 256;   // 40
    int b0 = t * PER;
    int s = 0;
    for (int i = 0; i < PER; ++i) {
        int idx = b0 + i;
        if (idx < Nn) s += deg[idx];
    }
    part[t] = s;
    __syncthreads();
    for (int o = 1; o < 256; o <<= 1) {
        int u = (t >= o) ? part[t - o] : 0;
        __syncthreads();
        part[t] += u;
        __syncthreads();
    }
    int run = part[t] - s;   // exclusive prefix
    for (int i = 0; i < PER; ++i) {
        int idx = b0 + i;
        if (idx < Nn) {
            rowptr[idx] = run;
            wptr[idx] = run;
            run += deg[idx];
        }
    }
    if (t == 255) rowptr[Nn] = run;
}

// Counting-sort scatter: srcs[] in dst-sorted order; epos[e] = sorted slot.
__global__ __launch_bounds__(256) void k_sort_edges(const int* __restrict__ ei,
                                                    int* __restrict__ wptr,
                                                    int* __restrict__ srcs,
                                                    int* __restrict__ epos) {
    int e = blockIdx.x * 256 + threadIdx.x;
    if (e >= Ee) return;
    int d = ei[Ee + e];
    int p = atomicAdd(&wptr[d], 1);
    srcs[p] = ei[e];
    epos[e] = p;
}

// Edge-direct message pass over dst-CSR. Grid = (157 node-blocks, nsplit).
// Block owns nodes [nbase, nbase+64); processes its sorted edge range in
// 64-edge tiles: gather -> MFMA (round-7 body) -> msg tile to LDS ->
// register segment-sum -> coalesced store of agg4[ksplit]. NO atomics.
__global__ __launch_bounds__(256, 5) void k_msg_nodes(const float* __restrict__ out,
                                                      const float* __restrict__ eh,
                                                      const unsigned short* __restrict__ Bfat,
                                                      const int* __restrict__ srcs,
                                                      const int* __restrict__ rowptr,
                                                      float* __restrict__ agg4,
                                                      int nsplit) {
    __shared__ float outs[64][64];    // gather/MFMA: f4 slot f at f^(el&7); msg phase: linear
    __shared__ float ehs_t[64][64];   // transposed: ehs_t[q][edge]
    int tid = threadIdx.x;
    int nbase = blockIdx.x * 64;
    int ksplit = blockIdx.y;
    int ks0 = (KSTEPS * ksplit) / nsplit;
    int ks1 = (KSTEPS * (ksplit + 1)) / nsplit;

    int rs = rowptr[nbase];
    int re = rowptr[min(nbase + 64, Nn)];
    int ecount = re - rs;
    int ntiles = (ecount + 63) >> 6;

    int lane = tid & 63;
    int wtile = tid >> 6;
    int m16 = lane & 15;
    int g = lane >> 4;
    int er = wtile * 16 + m16;
    int esw = er & 7;

    // segment-sum mapping: thread = (node nl, 16-col segment cs)
    int nl = tid >> 2;
    int cs = (tid & 3) * 16;
    int ng = nbase + nl;
    int gs = (ng < Nn) ? rowptr[ng] - rs : 0;
    int ge = (ng < Nn) ? rowptr[ng + 1] - rs : 0;
    float racc[16];
#pragma unroll
    for (int i = 0; i < 16; ++i) racc[i] = 0.f;

    for (int tile = 0; tile < ntiles; ++tile) {
        int tstart = tile << 6;
        {   // gather: 4 threads per edge row
            int el = tid >> 2, seg = tid & 3;
            int i = tstart + el;
            bool v = i < ecount;
            int ir = v ? rs + i : 0;
            int sN = srcs[ir];
            const float* orow = out + (size_t)sN * 64 + seg * 16;
            const float* erow = eh + (size_t)ir * 64 + seg * 16;
            float4 z = make_float4(0.f, 0.f, 0.f, 0.f);
#pragma unroll
            for (int c = 0; c < 4; ++c) {
                float4 ov = v ? *(const float4*)(orow + c * 4) : z;
                int f = (seg * 4 + c) ^ (el & 7);
                *(float4*)&outs[el][f * 4] = ov;
                float4 ev = v ? *(const float4*)(erow + c * 4) : z;
                int q = seg * 16 + c * 4;
                ehs_t[q + 0][el] = ev.x;
                ehs_t[q + 1][el] = ev.y;
                ehs_t[q + 2][el] = ev.z;
                ehs_t[q + 3][el] = ev.w;
            }
        }
        __syncthreads();

        f32x4_t acc[4];
#pragma unroll
        for (int nq = 0; nq < 4; ++nq) acc[nq] = (f32x4_t){0.f, 0.f, 0.f, 0.f};

        for (int ks = ks0; ks < ks1; ++ks) {
            float ehq; int fbase;
            if (ks < 128) { ehq = ehs_t[ks >> 1][er]; fbase = (ks & 1) * 8 + g * 2; }
            else          { ehq = 1.f;               fbase = (ks - 128) * 8 + g * 2; }
            float4 o1 = *(const float4*)&outs[er][(fbase ^ esw) * 4];
            float4 o2 = *(const float4*)&outs[er][((fbase + 1) ^ esw) * 4];
            float p[8] = {o1.x * ehq, o1.y * ehq, o1.z * ehq, o1.w * ehq,
                          o2.x * ehq, o2.y * ehq, o2.z * ehq, o2.w * ehq};
            bf16x8_t Ahi, Alo;
            split8(p, Ahi, Alo);
            const unsigned short* bstep = Bfat + (size_t)ks * 4096;
#pragma unroll
            for (int nq = 0; nq < 4; ++nq) {
                bf16x8_t bhi = *(const bf16x8_t*)(bstep + ((size_t)nq * 64 + lane) * 8);
                bf16x8_t blo = *(const bf16x8_t*)(bstep + ((size_t)(4 + nq) * 64 + lane) * 8);
                acc[nq] = __builtin_amdgcn_mfma_f32_16x16x32_bf16(Ahi, bhi, acc[nq], 0, 0, 0);
                acc[nq] = __builtin_amdgcn_mfma_f32_16x16x32_bf16(Ahi, blo, acc[nq], 0, 0, 0);
                acc[nq] = __builtin_amdgcn_mfma_f32_16x16x32_bf16(Alo, bhi, acc[nq], 0, 0, 0);
            }
        }
        __syncthreads();   // all waves done reading outs/ehs

        // dump msg tile into outs (linear layout)
#pragma unroll
        for (int nq = 0; nq < 4; ++nq)
#pragma unroll
            for (int r = 0; r < 4; ++r)
                outs[wtile * 16 + g * 4 + r][nq * 16 + m16] = acc[nq][r];
        __syncthreads();

        // per-node segment sum (rows of this tile belonging to node nl)
        int il = gs - tstart; if (il < 0) il = 0;
        int tcap = ecount - tstart; if (tcap > 64) tcap = 64;
        int ih = ge - tstart; if (ih > tcap) ih = tcap;
        for (int r = il; r < ih; ++r) {
#pragma unroll
            for (int c = 0; c < 4; ++c) {
                float4 mv = *(const float4*)&outs[r][cs + c * 4];
                racc[c * 4 + 0] += mv.x;
                racc[c * 4 + 1] += mv.y;
                racc[c * 4 + 2] += mv.z;
                racc[c * 4 + 3] += mv.w;
            }
        }
        __syncthreads();   // before next gather overwrites LDS
    }

    if (ng < Nn) {
        float* arow = agg4 + ((size_t)ksplit * Nn + ng) * 64 + cs;
#pragma unroll
        for (int c = 0; c < 4; ++c) {
            float4 sv = make_float4(racc[c * 4 + 0], racc[c * 4 + 1],
                                    racc[c * 4 + 2], racc[c * 4 + 3]);
            *(float4*)(arow + c * 4) = sv;
        }
    }
}

// Fused GRU: stage m = relu(sum_ks(agg4)/deg + b_conv) and h = out in LDS;
// gates via split-bf16 MFMA (A=[m|h] K=128, N=256); combine in epilogue.
__global__ __launch_bounds__(256) void k_gru_mfma(const float* __restrict__ agg4,
                                                  const int* __restrict__ rowptr,
                                                  const float* __restrict__ bconv,
                                                  const unsigned short* __restrict__ Wg,
                                                  const float* __restrict__ bih,
                                                  const float* __restrict__ bhh,
                                                  float* __restrict__ out,
                                                  int nsplit) {
    __shared__ float ms[64][68];
    __shared__ float hs[64][68];
    int tid = threadIdx.x;
    int nbase = blockIdx.x * 64;

    {   // stage: 4 threads per node, 16 cols each
        int nl = tid >> 2, seg = tid & 3;
        int ng = nbase + nl;
        bool v = ng < Nn;
        int dg = v ? rowptr[ng + 1] - rowptr[ng] : 1;
        if (dg < 1) dg = 1;
        float rc = 1.f / (float)dg;
        const float* hrow = out + (size_t)ng * 64 + seg * 16;
#pragma unroll
        for (int c4 = 0; c4 < 4; ++c4) {
            int col = seg * 16 + c4 * 4;
            float4 z = make_float4(0.f, 0.f, 0.f, 0.f);
            float4 av = z;
            for (int sp = 0; sp < nsplit; ++sp) {
                float4 t = v ? *(const float4*)(agg4 + ((size_t)sp * Nn + ng) * 64 + col) : z;
                av.x += t.x; av.y += t.y; av.z += t.z; av.w += t.w;
            }
            float4 hv = v ? *(const float4*)(hrow + c4 * 4) : z;
            ms[nl][col + 0] = fmaxf(av.x * rc + bconv[col + 0], 0.f);
            ms[nl][col + 1] = fmaxf(av.y * rc + bconv[col + 1], 0.f);
            ms[nl][col + 2] = fmaxf(av.z * rc + bconv[col + 2], 0.f);
            ms[nl][col + 3] = fmaxf(av.w * rc + bconv[col + 3], 0.f);
            *(float4*)&hs[nl][col] = hv;
        }
    }
    __syncthreads();

    int lane = tid & 63;
    int wtile = tid >> 6;
    int m16 = lane & 15;
    int g = lane >> 4;
    int er = wtile * 16 + m16;

    f32x4_t acc[16];
#pragma unroll
    for (int t = 0; t < 16; ++t) acc[t] = (f32x4_t){0.f, 0.f, 0.f, 0.f};

#pragma unroll
    for (int ks = 0; ks < 4; ++ks) {
        const float* src = (ks < 2) ? &ms[er][ks * 32 + g * 8]
                                    : &hs[er][(ks - 2) * 32 + g * 8];
        float p[8];
#pragma unroll
        for (int ii = 0; ii < 8; ++ii) p[ii] = src[ii];
        bf16x8_t Ahi, Alo;
        split8(p, Ahi, Alo);
        const unsigned short* bstep = Wg + (size_t)ks * (2 * 16 * 512);
#pragma unroll
        for (int t = 0; t < 16; ++t) {
            bf16x8_t bhi = *(const bf16x8_t*)(bstep + ((size_t)t * 64 + lane) * 8);
            bf16x8_t blo = *(const bf16x8_t*)(bstep + ((size_t)(16 + t) * 64 + lane) * 8);
            acc[t] = __builtin_amdgcn_mfma_f32_16x16x32_bf16(Ahi, bhi, acc[t], 0, 0, 0);
            acc[t] = __builtin_amdgcn_mfma_f32_16x16x32_bf16(Ahi, blo, acc[t], 0, 0, 0);
            acc[t] = __builtin_amdgcn_mfma_f32_16x16x32_bf16(Alo, bhi, acc[t], 0, 0, 0);
        }
    }

    // epilogue: GRU combine, fully lane-local
#pragma unroll
    for (int t2 = 0; t2 < 4; ++t2) {
        int jj = t2 * 16 + m16;
        float br = bih[jj] + bhh[jj];
        float bz = bih[64 + jj] + bhh[64 + jj];
        float bin_ = bih[128 + jj];
        float bhn = bhh[128 + jj];
#pragma unroll
        for (int r = 0; r < 4; ++r) {
            int nl2 = wtile * 16 + g * 4 + r;
            int ng2 = nbase + nl2;
            if (ng2 >= Nn) continue;
            float rg = sigmoidf_(acc[t2][r] + br);
            float z  = sigmoidf_(acc[4 + t2][r] + bz);
            float nn = tanhf(acc[8 + t2][r] + bin_ + rg * (acc[12 + t2][r] + bhn));
            float hv = hs[nl2][jj];
            out[(size_t)ng2 * 64 + jj] = (1.f - z) * nn + z * hv;
        }
    }
}

__global__ __launch_bounds__(256) void k_count_batch(const int* __restrict__ batch,
                                                     int* __restrict__ bcount) {
    int n = blockIdx.x * 256 + threadIdx.x;
    if (n >= Nn) return;
    atomicAdd(&bcount[batch[n]], 1);
}

// One-wave parallel exclusive scan over Bb=400 counts.
__global__ __launch_bounds__(64) void k_scan_batch(const int* __restrict__ bcount,
                                                   int* __restrict__ bstart) {
    int lane = threadIdx.x;
    const int PER = (Bb + 63) / 64;   // 7
    int base = lane * PER;
    int v[PER];
    int s = 0;
#pragma unroll
    for (int i = 0; i < PER; ++i) {
        int idx = base + i;
        int c = (idx < Bb) ? bcount[idx] : 0;
        v[i] = s;
        s += c;
    }
    int inc = s;
#pragma unroll
    for (int o = 1; o < 64; o <<= 1) {
        int t = __shfl_up(inc, o, 64);
        if (lane >= o) inc += t;
    }
    int excl = inc - s;
    int total = __shfl(inc, 63, 64);
#pragma unroll
    for (int i = 0; i < PER; ++i) {
        int idx = base + i;
        if (idx < Bb) bstart[idx] = excl + v[i];
    }
    if (lane == 63) bstart[Bb] = total;
}

// Block-wide reductions (uniform result broadcast to all 256 threads).
__device__ __forceinline__ float block_reduce_max_(float v, float* red, int tid) {
#pragma unroll
    for (int o = 32; o; o >>= 1) v = fmaxf(v, __shfl_xor(v, o, 64));
    if ((tid & 63) == 0) red[tid >> 6] = v;
    __syncthreads();
    float r = fmaxf(fmaxf(red[0], red[1]), fmaxf(red[2], red[3]));
    __syncthreads();
    return r;
}
__device__ __forceinline__ float block_reduce_sum_(float v, float* red, int tid) {
#pragma unroll
    for (int o = 32; o; o >>= 1) v += __shfl_xor(v, o, 64);
    if ((tid & 63) == 0) red[tid >> 6] = v;
    __syncthreads();
    float r = (red[0] + red[1]) + (red[2] + red[3]);
    __syncthreads();
    return r;
}

// Fused Set2Set: one 256-thread block per graph (round 6, validated).
__global__ __launch_bounds__(256) void k_set2set(const float* __restrict__ out,
                                                 const int* __restrict__ bstart,
                                                 const float* __restrict__ Wil,
                                                 const float* __restrict__ bil,
                                                 const float* __restrict__ Whl,
                                                 const float* __restrict__ bhl,
                                                 const float* __restrict__ Wo1,
                                                 const float* __restrict__ bo1,
                                                 const float* __restrict__ Wo2,
                                                 const float* __restrict__ bo2,
                                                 float* __restrict__ outp) {
    __shared__ float qs[128];        // q_star = [q | r]
    __shared__ float hs2[64];        // hl
    __shared__ float cs[64];         // cl
    __shared__ float g_lds[256];     // LSTM gates
    __shared__ float e_lds[S2S_CHUNK];
    __shared__ float red[4];
    __shared__ float rpart[4][64];

    int b = blockIdx.x, tid = threadIdx.x;
    int lane = tid & 63, wv = tid >> 6;
    int s = bstart[b], eend = bstart[b + 1];
    int cntb = eend - s;

    if (tid < 128) qs[tid] = 0.f;
    if (tid < 64) { hs2[tid] = 0.f; cs[tid] = 0.f; }
    __syncthreads();

    for (int step = 0; step < 3; ++step) {
        {
            int u = tid;
            float acc = bil[u] + bhl[u];
            const float4* wi = (const float4*)(Wil + (size_t)u * 128);
#pragma unroll
            for (int k4 = 0; k4 < 32; ++k4) {
                float4 w = wi[k4];
                acc += qs[k4 * 4 + 0] * w.x + qs[k4 * 4 + 1] * w.y +
                       qs[k4 * 4 + 2] * w.z + qs[k4 * 4 + 3] * w.w;
            }
            const float4* wh = (const float4*)(Whl + (size_t)u * 64);
#pragma unroll
            for (int k4 = 0; k4 < 16; ++k4) {
                float4 w = wh[k4];
                acc += hs2[k4 * 4 + 0] * w.x + hs2[k4 * 4 + 1] * w.y +
                       hs2[k4 * 4 + 2] * w.z + hs2[k4 * 4 + 3] * w.w;
            }
            g_lds[u] = acc;
        }
        __syncthreads();
        if (tid < 64) {   // torch order i,f,g,o
            float c = sigmoidf_(g_lds[64 + tid]) * cs[tid] +
                      sigmoidf_(g_lds[tid]) * tanhf(g_lds[128 + tid]);
            cs[tid] = c;
            float h = sigmoidf_(g_lds[192 + tid]) * tanhf(c);
            hs2[tid] = h;
            qs[tid] = h;   // q = hl
        }
        __syncthreads();

        // attention: chunked two-pass softmax, node-parallel
        float gmax = -INFINITY, gsum = 0.f, racc = 0.f;
        for (int c0 = s; c0 < eend; c0 += S2S_CHUNK) {
            int clen = min(S2S_CHUNK, eend - c0);
            for (int i = tid; i < clen; i += 256) {
                const float4* orow = (const float4*)(out + (size_t)(c0 + i) * 64);
                float a0 = 0.f, a1 = 0.f, a2 = 0.f, a3 = 0.f;
#pragma unroll
                for (int k4 = 0; k4 < 16; k4 += 4) {
                    float4 o0 = orow[k4], o1 = orow[k4 + 1], o2 = orow[k4 + 2], o3 = orow[k4 + 3];
                    a0 += o0.x * qs[k4 * 4 + 0]  + o0.y * qs[k4 * 4 + 1]  + o0.z * qs[k4 * 4 + 2]  + o0.w * qs[k4 * 4 + 3];
                    a1 += o1.x * qs[k4 * 4 + 4]  + o1.y * qs[k4 * 4 + 5]  + o1.z * qs[k4 * 4 + 6]  + o1.w * qs[k4 * 4 + 7];
                    a2 += o2.x * qs[k4 * 4 + 8]  + o2.y * qs[k4 * 4 + 9]  + o2.z * qs[k4 * 4 + 10] + o2.w * qs[k4 * 4 + 11];
                    a3 += o3.x * qs[k4 * 4 + 12] + o3.y * qs[k4 * 4 + 13] + o3.z * qs[k4 * 4 + 14] + o3.w * qs[k4 * 4 + 15];
                }
                e_lds[i] = (a0 + a1) + (a2 + a3);
            }
            __syncthreads();
            float m = -INFINITY;
            for (int i = tid; i < clen; i += 256) m = fmaxf(m, e_lds[i]);
            float cmax = block_reduce_max_(m, red, tid);
            float nm = fmaxf(gmax, cmax);
            float scale = expf(gmax - nm);   // 0 on first chunk (gmax=-inf)
            gsum *= scale; racc *= scale;
            float lsum = 0.f;
            for (int i = tid; i < clen; i += 256) {
                float av = expf(e_lds[i] - nm);
                e_lds[i] = av;
                lsum += av;
            }
            gsum += block_reduce_sum_(lsum, red, tid);
            for (int i = wv; i < clen; i += 4)
                racc += e_lds[i] * out[(size_t)(c0 + i) * 64 + lane];
            gmax = nm;
            __syncthreads();
        }
        rpart[wv][lane] = racc;
        __syncthreads();
        if (tid < 64) {
            float r = (rpart[0][tid] + rpart[1][tid]) + (rpart[2][tid] + rpart[3][tid]);
            qs[64 + tid] = (cntb > 0) ? r / gsum : 0.f;
        }
        __syncthreads();
    }

    // final MLP (wave 0)
    if (tid < 64) {
        float acc = bo1[tid];
        const float4* w = (const float4*)(Wo1 + (size_t)tid * 128);
#pragma unroll
        for (int k4 = 0; k4 < 32; ++k4) {
            float4 wv4 = w[k4];
            acc += qs[k4 * 4 + 0] * wv4.x + qs[k4 * 4 + 1] * wv4.y +
                   qs[k4 * 4 + 2] * wv4.z + qs[k4 * 4 + 3] * wv4.w;
        }
        acc = fmaxf(acc, 0.f);
        float t = acc * Wo2[tid];
#pragma unroll
        for (int o = 32; o; o >>= 1) t += __shfl_xor(t, o, 64);
        if (tid == 0) outp[b] = t + bo2[0];
    }
}

extern "C" void kernel_launch(void* const* d_in, const int* in_sizes, int n_in,
                              void* d_out, int out_size, void* d_ws, size_t ws_size,
                              hipStream_t stream) {
    const float* x        = (const float*)d_in[0];
    const float* ea       = (const float*)d_in[1];
    const float* W_in     = (const float*)d_in[2];
    const float* b_in     = (const float*)d_in[3];
    const float* W_e1     = (const float*)d_in[4];
    const float* b_e1     = (const float*)d_in[5];
    const float* W_e2     = (const float*)d_in[6];
    const float* b_e2     = (const float*)d_in[7];
    const float* b_conv   = (const float*)d_in[8];
    const float* W_ih     = (const float*)d_in[9];
    const float* b_ih     = (const float*)d_in[10];
    const float* W_hh     = (const float*)d_in[11];
    const float* b_hh     = (const float*)d_in[12];
    const float* W_ih_l   = (const float*)d_in[13];
    const float* b_ih_l   = (const float*)d_in[14];
    const float* W_hh_l   = (const float*)d_in[15];
    const float* b_hh_l   = (const float*)d_in[16];
    const float* W_o1     = (const float*)d_in[17];
    const float* b_o1     = (const float*)d_in[18];
    const float* W_o2     = (const float*)d_in[19];
    const float* b_o2     = (const float*)d_in[20];
    const int*   ei       = (const int*)d_in[21];
    const int*   batch    = (const int*)d_in[22];
    float* outp = (float*)d_out;

    char* base = (char*)d_ws;
    size_t off = 0;
    auto carve = [&](size_t bytes) -> void* {
        void* p = base + off;
        off = (off + bytes + 255) & ~(size_t)255;
        return p;
    };

    // pick largest nsplit whose workspace fits
    int ns = 8;
    float *out, *agg4, *eh;
    unsigned short *Bfat, *Wg;
    int *srcs, *epos, *rowptr, *wptr, *deg, *bcount, *bstart;
    for (;; ns >>= 1) {
        off = 0;
        out    = (float*)carve((size_t)Nn * 64 * 4);
        agg4   = (float*)carve((size_t)ns * Nn * 64 * 4);
        eh     = (float*)carve((size_t)Ee * 64 * 4);
        Bfat   = (unsigned short*)carve((size_t)KSTEPS * 4096 * 2);
        Wg     = (unsigned short*)carve((size_t)4 * 2 * 16 * 64 * 8 * 2);
        srcs   = (int*)carve((size_t)Ee * 4);
        epos   = (int*)carve((size_t)Ee * 4);
        rowptr = (int*)carve((size_t)(Nn + 1) * 4);
        wptr   = (int*)carve((size_t)Nn * 4);
        deg    = (int*)carve((size_t)Nn * 4);
        bcount = (int*)carve((size_t)Bb * 4);
        bstart = (int*)carve((size_t)(Bb + 1) * 4);
        if (off <= ws_size || ns == 1) break;
    }
    if (off > ws_size) return;

    hipMemsetAsync(deg, 0, (size_t)Nn * 4, stream);
    hipMemsetAsync(bcount, 0, (size_t)Bb * 4, stream);

    k_count_deg<<<(Ee + 255) / 256, 256, 0, stream>>>(ei, deg);
    k_scan_nodes<<<1, 256, 0, stream>>>(deg, rowptr, wptr);
    k_sort_edges<<<(Ee + 255) / 256, 256, 0, stream>>>(ei, wptr, srcs, epos);

    k_in_linear<<<(Nn * 64) / 256, 256, 0, stream>>>(x, W_in, b_in, out);
    k_edge_mlp1<<<(Ee * 64) / 256, 256, 0, stream>>>(ea, W_e1, b_e1, epos, eh);
    k_make_Bfat<<<(KSTEPS * 4096) / 256, 256, 0, stream>>>(W_e2, b_e2, Bfat);
    k_make_Wg<<<(4 * 2 * 16 * 64 * 8) / 256, 256, 0, stream>>>(W_ih, W_hh, Wg);
    k_count_batch<<<(Nn + 255) / 256, 256, 0, stream>>>(batch, bcount);
    k_scan_batch<<<1, 64, 0, stream>>>(bcount, bstart);

    int nblocks = (Nn + 63) / 64;   // 157
    for (int it = 0; it < 3; ++it) {
        k_msg_nodes<<<dim3(nblocks, ns), 256, 0, stream>>>(out, eh, Bfat, srcs, rowptr, agg4, ns);
        k_gru_mfma<<<nblocks, 256, 0, stream>>>(agg4, rowptr, b_conv, Wg, b_ih, b_hh, out, ns);
    }

    k_set2set<<<Bb, 256, 0, stream>>>(out, bstart, W_ih_l, b_ih_l, W_hh_l, b_hh_l,
                                      W_o1, b_o1, W_o2, b_o2, outp);
}

// Round 4
// 335.880 us; speedup vs baseline: 1.7629x; 1.7629x over previous
//
#include <hip/hip_runtime.h>
#include <math.h>

// MPNN forward. Round 9:
//  - REVERT R8 CSR rewrite (134us: 8x gather duplication, transposed-ehs bank
//    conflicts, extra barriers). Back to R7 edge-block structure.
//  - k_msg_mfma: B-panel amortization. R7 was L2-stream-bound: each wave read
//    the full 8KB Bfat step per ks => 1.32 GB/dispatch from L2 (~38us at 34.5
//    TB/s) -- explains occupancy-insensitive 72us. Now: 128 edges/block
//    (2 M-tiles/wave) + B staged in LDS once per block per ks with register
//    double-prefetch (load next-ks B during MFMA phase, ds_write after
//    barrier). B global traffic 1.32GB -> 166MB; LDS 50KB -> 3 blocks/CU,
//    628-block grid fully resident.
//  - Round 7: outs XOR-swizzle, compact ehs q-window. Round 6: k_set2set
//    256-thr node-parallel softmax, one-wave shfl scan. Rounds 1-5: K-split
//    edge MFMA, fused GRU MFMA, split-bf16 hi/lo MFMA, Bfat/Wg pre-pack.

#define Nn 10000
#define Ee 20000
#define Bb 400
#define KSTEPS 130   // 128 (q,d) steps + 2 bias steps (K = 4160)
#define S2S_CHUNK 1024

typedef __attribute__((ext_vector_type(8))) short bf16x8_t;
typedef __attribute__((ext_vector_type(4))) float f32x4_t;

__device__ __forceinline__ float sigmoidf_(float x) { return 1.f / (1.f + expf(-x)); }

// split 8 fp32 -> hi/lo bf16x8 fragments (validated round 4, absmax 0.0)
__device__ __forceinline__ void split8(const float* p, bf16x8_t& Ahi_, bf16x8_t& Alo_) {
    union { bf16x8_t v; unsigned u[4]; } hi, lo;
#pragma unroll
    for (int ii = 0; ii < 4; ++ii) {
        float pa = p[2 * ii], pb = p[2 * ii + 1];
        unsigned ua = __float_as_uint(pa), ub = __float_as_uint(pb);
        hi.u[ii] = (ua >> 16) | (ub & 0xFFFF0000u);
        float la = pa - __uint_as_float(ua & 0xFFFF0000u);
        float lb = pb - __uint_as_float(ub & 0xFFFF0000u);
        lo.u[ii] = (__float_as_uint(la) >> 16) | (__float_as_uint(lb) & 0xFFFF0000u);
    }
    Ahi_ = hi.v; Alo_ = lo.v;
}

__global__ __launch_bounds__(256) void k_in_linear(const float* __restrict__ x,
                                                   const float* __restrict__ Win,
                                                   const float* __restrict__ bin,
                                                   float* __restrict__ out) {
    int idx = blockIdx.x * 256 + threadIdx.x;
    if (idx >= Nn * 64) return;
    int n = idx >> 6, j = idx & 63;
    const float* xr = x + n * 32;
    const float* w = Win + j * 32;
    float acc = bin[j];
#pragma unroll
    for (int k = 0; k < 32; ++k) acc += xr[k] * w[k];
    out[idx] = fmaxf(acc, 0.f);
}

__global__ __launch_bounds__(256) void k_edge_mlp1(const float* __restrict__ ea,
                                                   const float* __restrict__ W1,
                                                   const float* __restrict__ b1,
                                                   float* __restrict__ eh) {
    int idx = blockIdx.x * 256 + threadIdx.x;
    if (idx >= Ee * 64) return;
    int e = idx >> 6, j = idx & 63;
    const float* ar = ea + e * 16;
    const float* w = W1 + j * 16;
    float acc = b1[j];
#pragma unroll
    for (int k = 0; k < 16; ++k) acc += ar[k] * w[k];
    eh[idx] = fmaxf(acc, 0.f);
}

// Bfat[kstep][h][nq][lane][i] (bf16), as round 4 (validated).
__global__ __launch_bounds__(256) void k_make_Bfat(const float* __restrict__ W2,
                                                   const float* __restrict__ b2,
                                                   unsigned short* __restrict__ Bfat) {
    int idx = blockIdx.x * 256 + threadIdx.x;
    if (idx >= KSTEPS * 4096) return;
    int i  = idx & 7;
    int l  = (idx >> 3) & 63;
    int nq = (idx >> 9) & 3;
    int h  = (idx >> 11) & 1;
    int ks = idx >> 12;
    int kap = ks * 32 + (l >> 4) * 8 + i;
    int f = nq * 16 + (l & 15);
    float w;
    if (kap < 4096) {
        int q = kap >> 6, d = kap & 63;
        w = W2[(size_t)(d * 64 + f) * 64 + q];
    } else {
        int d = kap - 4096;
        w = b2[d * 64 + f];
    }
    unsigned u = __float_as_uint(w);
    unsigned short outv;
    if (h == 0) {
        outv = (unsigned short)(u >> 16);
    } else {
        float lo = w - __uint_as_float(u & 0xFFFF0000u);
        outv = (unsigned short)(__float_as_uint(lo) >> 16);
    }
    Bfat[idx] = outv;
}

// Wg[ks][h][t][lane][i] (bf16): GRU-gates B table, N=256 cols:
//  t 0-3: i_r+h_r (k<64: W_ih[j][k], k>=64: W_hh[j][k-64])
//  t 4-7: i_z+h_z; t 8-11: i_n only; t 12-15: h_n only.
__global__ __launch_bounds__(256) void k_make_Wg(const float* __restrict__ Wih,
                                                 const float* __restrict__ Whh,
                                                 unsigned short* __restrict__ Wg) {
    int idx = blockIdx.x * 256 + threadIdx.x;
    if (idx >= 4 * 2 * 16 * 64 * 8) return;
    int i  = idx & 7;
    int l  = (idx >> 3) & 63;
    int t  = (idx >> 9) & 15;
    int h  = (idx >> 13) & 1;
    int ks = idx >> 14;
    int k = ks * 32 + (l >> 4) * 8 + i;
    int u = t * 16 + (l & 15);
    int j = u & 63, part = u >> 6;   // 0:r, 1:z, 2:i_n, 3:h_n
    float w = 0.f;
    if (part == 0) w = (k < 64) ? Wih[(size_t)j * 64 + k]          : Whh[(size_t)j * 64 + (k - 64)];
    if (part == 1) w = (k < 64) ? Wih[(size_t)(64 + j) * 64 + k]   : Whh[(size_t)(64 + j) * 64 + (k - 64)];
    if (part == 2) w = (k < 64) ? Wih[(size_t)(128 + j) * 64 + k]  : 0.f;
    if (part == 3) w = (k < 64) ? 0.f : Whh[(size_t)(128 + j) * 64 + (k - 64)];
    unsigned uu = __float_as_uint(w);
    unsigned short outv;
    if (h == 0) {
        outv = (unsigned short)(uu >> 16);
    } else {
        float lo = w - __uint_as_float(uu & 0xFFFF0000u);
        outv = (unsigned short)(__float_as_uint(lo) >> 16);
    }
    Wg[idx] = outv;
}

// Edge-direct message pass, K-split x4 across blockIdx.y, 128 edges/block.
// B-step (8KB) staged in LDS once per block per ks, register double-prefetch.
__global__ __launch_bounds__(256, 3) void k_msg_mfma(const float* __restrict__ out,
                                                     const float* __restrict__ eh,
                                                     const unsigned short* __restrict__ Bfat,
                                                     const int* __restrict__ ei,
                                                     float* __restrict__ agg) {
    __shared__ float outs[128][64];        // row el: f4 slot f stored at f ^ (el&7)
    __shared__ float ehs[128][20];         // compact q-window [q0, q0+qn)
    __shared__ unsigned short Bst[4096];   // staged B for current ks (8KB)
    int tid = threadIdx.x;
    int ebase = blockIdx.x * 128;
    int ksplit = blockIdx.y;

    int ks0 = ksplit * 32 + (ksplit < 2 ? ksplit : 2);      // 0,33,66,98
    int ks1 = ks0 + (ksplit < 2 ? 33 : 32);                 // 33,66,98,130
    int q0 = ks0 >> 1;
    int qn = ((min(ks1, 128) - 1) >> 1) - q0 + 1;           // <= 17

    // gather 128 edges: 4 threads per edge, two passes
#pragma unroll
    for (int pass = 0; pass < 2; ++pass) {
        int el = pass * 64 + (tid >> 2), seg = tid & 3;
        int eg = ebase + el;
        bool v = eg < Ee;
        int s = v ? ei[eg] : 0;
        const float* orow = out + (size_t)s * 64 + seg * 16;
        float4 z = make_float4(0.f, 0.f, 0.f, 0.f);
#pragma unroll
        for (int c = 0; c < 4; ++c) {
            float4 ov = v ? *(const float4*)(orow + c * 4) : z;
            int f = (seg * 4 + c) ^ (el & 7);
            *(float4*)&outs[el][f * 4] = ov;
        }
        const float* erow = eh + (size_t)eg * 64;
        for (int j = seg; j < qn; j += 4)
            ehs[el][j] = v ? erow[q0 + j] : 0.f;
    }

    // prefetch B[ks0] into registers (16B x2 per thread = 8KB per block)
    const float4* bsrc = (const float4*)(Bfat + (size_t)ks0 * 4096);
    float4 bpre0 = bsrc[tid];
    float4 bpre1 = bsrc[256 + tid];

    int lane = tid & 63;
    int wtile = tid >> 6;
    int m16 = lane & 15;
    int g = lane >> 4;
    int erA = wtile * 32 + m16;
    int erB = erA + 16;
    int eswA = erA & 7;
    int eswB = erB & 7;

    f32x4_t acc[2][4];
#pragma unroll
    for (int t = 0; t < 2; ++t)
#pragma unroll
        for (int nq = 0; nq < 4; ++nq) acc[t][nq] = (f32x4_t){0.f, 0.f, 0.f, 0.f};

    for (int ks = ks0; ks < ks1; ++ks) {
        // commit staged B to LDS, make visible (also covers gather on 1st iter)
        *(float4*)&Bst[(size_t)tid * 8] = bpre0;
        *(float4*)&Bst[2048 + (size_t)tid * 8] = bpre1;
        __syncthreads();

        // prefetch next ks during compute (latency hidden under MFMA)
        if (ks + 1 < ks1) {
            const float4* bn = (const float4*)(Bfat + (size_t)(ks + 1) * 4096);
            bpre0 = bn[tid];
            bpre1 = bn[256 + tid];
        }

        // B fragments from LDS (shared by both M-tiles), lane-contiguous 16B
        bf16x8_t bhi[4], blo[4];
#pragma unroll
        for (int nq = 0; nq < 4; ++nq) {
            bhi[nq] = *(const bf16x8_t*)&Bst[((size_t)nq * 64 + lane) * 8];
            blo[nq] = *(const bf16x8_t*)&Bst[((size_t)(4 + nq) * 64 + lane) * 8];
        }

        int fbase = (ks < 128) ? (ks & 1) * 8 + g * 2 : (ks - 128) * 8 + g * 2;

        {   // M-tile A
            float ehq = (ks < 128) ? ehs[erA][(ks >> 1) - q0] : 1.f;
            float4 o1 = *(const float4*)&outs[erA][(fbase ^ eswA) * 4];
            float4 o2 = *(const float4*)&outs[erA][((fbase + 1) ^ eswA) * 4];
            float p[8] = {o1.x * ehq, o1.y * ehq, o1.z * ehq, o1.w * ehq,
                          o2.x * ehq, o2.y * ehq, o2.z * ehq, o2.w * ehq};
            bf16x8_t Ahi, Alo;
            split8(p, Ahi, Alo);
#pragma unroll
            for (int nq = 0; nq < 4; ++nq) {
                acc[0][nq] = __builtin_amdgcn_mfma_f32_16x16x32_bf16(Ahi, bhi[nq], acc[0][nq], 0, 0, 0);
                acc[0][nq] = __builtin_amdgcn_mfma_f32_16x16x32_bf16(Ahi, blo[nq], acc[0][nq], 0, 0, 0);
                acc[0][nq] = __builtin_amdgcn_mfma_f32_16x16x32_bf16(Alo, bhi[nq], acc[0][nq], 0, 0, 0);
            }
        }
        {   // M-tile B
            float ehq = (ks < 128) ? ehs[erB][(ks >> 1) - q0] : 1.f;
            float4 o1 = *(const float4*)&outs[erB][(fbase ^ eswB) * 4];
            float4 o2 = *(const float4*)&outs[erB][((fbase + 1) ^ eswB) * 4];
            float p[8] = {o1.x * ehq, o1.y * ehq, o1.z * ehq, o1.w * ehq,
                          o2.x * ehq, o2.y * ehq, o2.z * ehq, o2.w * ehq};
            bf16x8_t Ahi, Alo;
            split8(p, Ahi, Alo);
#pragma unroll
            for (int nq = 0; nq < 4; ++nq) {
                acc[1][nq] = __builtin_amdgcn_mfma_f32_16x16x32_bf16(Ahi, bhi[nq], acc[1][nq], 0, 0, 0);
                acc[1][nq] = __builtin_amdgcn_mfma_f32_16x16x32_bf16(Ahi, blo[nq], acc[1][nq], 0, 0, 0);
                acc[1][nq] = __builtin_amdgcn_mfma_f32_16x16x32_bf16(Alo, bhi[nq], acc[1][nq], 0, 0, 0);
            }
        }
        __syncthreads();   // protect Bst before next commit
    }

#pragma unroll
    for (int t = 0; t < 2; ++t) {
#pragma unroll
        for (int r = 0; r < 4; ++r) {
            int el = wtile * 32 + t * 16 + g * 4 + r;
            int eg = ebase + el;
            if (eg >= Ee) continue;
            int dn = ei[Ee + eg];
#pragma unroll
            for (int nq = 0; nq < 4; ++nq)
                atomicAdd(&agg[(size_t)dn * 64 + nq * 16 + m16], acc[t][nq][r]);
        }
    }
}

// Fused GRU: stage m = relu(agg/cnt + b_conv) and h = out in LDS; gates via
// split-bf16 MFMA (A=[m|h] K=128, N=256); combine in epilogue; out updated.
__global__ __launch_bounds__(256) void k_gru_mfma(const float* __restrict__ agg,
                                                  const float* __restrict__ cnt,
                                                  const float* __restrict__ bconv,
                                                  const unsigned short* __restrict__ Wg,
                                                  const float* __restrict__ bih,
                                                  const float* __restrict__ bhh,
                                                  float* __restrict__ out) {
    __shared__ float ms[64][68];
    __shared__ float hs[64][68];
    int tid = threadIdx.x;
    int nbase = blockIdx.x * 64;

    {   // stage: 4 threads per node, 16 cols each
        int nl = tid >> 2, seg = tid & 3;
        int ng = nbase + nl;
        bool v = ng < Nn;
        float c = v ? cnt[ng] : 1.f;
        c = c < 1.f ? 1.f : c;
        float rc = 1.f / c;
        const float* arow = agg + (size_t)ng * 64 + seg * 16;
        const float* hrow = out + (size_t)ng * 64 + seg * 16;
#pragma unroll
        for (int c4 = 0; c4 < 4; ++c4) {
            int col = seg * 16 + c4 * 4;
            float4 z = make_float4(0.f, 0.f, 0.f, 0.f);
            float4 av = v ? *(const float4*)(arow + c4 * 4) : z;
            float4 hv = v ? *(const float4*)(hrow + c4 * 4) : z;
            ms[nl][col + 0] = fmaxf(av.x * rc + bconv[col + 0], 0.f);
            ms[nl][col + 1] = fmaxf(av.y * rc + bconv[col + 1], 0.f);
            ms[nl][col + 2] = fmaxf(av.z * rc + bconv[col + 2], 0.f);
            ms[nl][col + 3] = fmaxf(av.w * rc + bconv[col + 3], 0.f);
            *(float4*)&hs[nl][col] = hv;
        }
    }
    __syncthreads();

    int lane = tid & 63;
    int wtile = tid >> 6;
    int m16 = lane & 15;
    int g = lane >> 4;
    int er = wtile * 16 + m16;

    f32x4_t acc[16];
#pragma unroll
    for (int t = 0; t < 16; ++t) acc[t] = (f32x4_t){0.f, 0.f, 0.f, 0.f};

#pragma unroll
    for (int ks = 0; ks < 4; ++ks) {
        const float* src = (ks < 2) ? &ms[er][ks * 32 + g * 8]
                                    : &hs[er][(ks - 2) * 32 + g * 8];
        float p[8];
#pragma unroll
        for (int ii = 0; ii < 8; ++ii) p[ii] = src[ii];
        bf16x8_t Ahi, Alo;
        split8(p, Ahi, Alo);
        const unsigned short* bstep = Wg + (size_t)ks * (2 * 16 * 512);
#pragma unroll
        for (int t = 0; t < 16; ++t) {
            bf16x8_t bhi = *(const bf16x8_t*)(bstep + ((size_t)t * 64 + lane) * 8);
            bf16x8_t blo = *(const bf16x8_t*)(bstep + ((size_t)(16 + t) * 64 + lane) * 8);
            acc[t] = __builtin_amdgcn_mfma_f32_16x16x32_bf16(Ahi, bhi, acc[t], 0, 0, 0);
            acc[t] = __builtin_amdgcn_mfma_f32_16x16x32_bf16(Ahi, blo, acc[t], 0, 0, 0);
            acc[t] = __builtin_amdgcn_mfma_f32_16x16x32_bf16(Alo, bhi, acc[t], 0, 0, 0);
        }
    }

    // epilogue: GRU combine, fully lane-local
#pragma unroll
    for (int t2 = 0; t2 < 4; ++t2) {
        int jj = t2 * 16 + m16;
        float br = bih[jj] + bhh[jj];
        float bz = bih[64 + jj] + bhh[64 + jj];
        float bin_ = bih[128 + jj];
        float bhn = bhh[128 + jj];
#pragma unroll
        for (int r = 0; r < 4; ++r) {
            int nl2 = wtile * 16 + g * 4 + r;
            int ng2 = nbase + nl2;
            if (ng2 >= Nn) continue;
            float rg = sigmoidf_(acc[t2][r] + br);
            float z  = sigmoidf_(acc[4 + t2][r] + bz);
            float nn = tanhf(acc[8 + t2][r] + bin_ + rg * (acc[12 + t2][r] + bhn));
            float hv = hs[nl2][jj];
            out[(size_t)ng2 * 64 + jj] = (1.f - z) * nn + z * hv;
        }
    }
}

__global__ __launch_bounds__(256) void k_count_deg(const int* __restrict__ ei,
                                                   float* __restrict__ cnt) {
    int e = blockIdx.x * 256 + threadIdx.x;
    if (e >= Ee) return;
    atomicAdd(&cnt[ei[Ee + e]], 1.f);
}

__global__ __launch_bounds__(256) void k_count_batch(const int* __restrict__ batch,
                                                     int* __restrict__ bcount) {
    int n = blockIdx.x * 256 + threadIdx.x;
    if (n >= Nn) return;
    atomicAdd(&bcount[batch[n]], 1);
}

// One-wave parallel exclusive scan over Bb=400 counts.
__global__ __launch_bounds__(64) void k_scan_batch(const int* __restrict__ bcount,
                                                   int* __restrict__ bstart) {
    int lane = threadIdx.x;
    const int PER = (Bb + 63) / 64;   // 7
    int base = lane * PER;
    int v[PER];
    int s = 0;
#pragma unroll
    for (int i = 0; i < PER; ++i) {
        int idx = base + i;
        int c = (idx < Bb) ? bcount[idx] : 0;
        v[i] = s;
        s += c;
    }
    int inc = s;
#pragma unroll
    for (int o = 1; o < 64; o <<= 1) {
        int t = __shfl_up(inc, o, 64);
        if (lane >= o) inc += t;
    }
    int excl = inc - s;
    int total = __shfl(inc, 63, 64);
#pragma unroll
    for (int i = 0; i < PER; ++i) {
        int idx = base + i;
        if (idx < Bb) bstart[idx] = excl + v[i];
    }
    if (lane == 63) bstart[Bb] = total;
}

// Block-wide reductions (uniform result broadcast to all 256 threads).
__device__ __forceinline__ float block_reduce_max_(float v, float* red, int tid) {
#pragma unroll
    for (int o = 32; o; o >>= 1) v = fmaxf(v, __shfl_xor(v, o, 64));
    if ((tid & 63) == 0) red[tid >> 6] = v;
    __syncthreads();
    float r = fmaxf(fmaxf(red[0], red[1]), fmaxf(red[2], red[3]));
    __syncthreads();
    return r;
}
__device__ __forceinline__ float block_reduce_sum_(float v, float* red, int tid) {
#pragma unroll
    for (int o = 32; o; o >>= 1) v += __shfl_xor(v, o, 64);
    if ((tid & 63) == 0) red[tid >> 6] = v;
    __syncthreads();
    float r = (red[0] + red[1]) + (red[2] + red[3]);
    __syncthreads();
    return r;
}

// Fused Set2Set: one 256-thread block per graph (round 6, validated).
__global__ __launch_bounds__(256) void k_set2set(const float* __restrict__ out,
                                                 const int* __restrict__ bstart,
                                                 const float* __restrict__ Wil,
                                                 const float* __restrict__ bil,
                                                 const float* __restrict__ Whl,
                                                 const float* __restrict__ bhl,
                                                 const float* __restrict__ Wo1,
                                                 const float* __restrict__ bo1,
                                                 const float* __restrict__ Wo2,
                                                 const float* __restrict__ bo2,
                                                 float* __restrict__ outp) {
    __shared__ float qs[128];        // q_star = [q | r]
    __shared__ float hs2[64];        // hl
    __shared__ float cs[64];         // cl
    __shared__ float g_lds[256];     // LSTM gates
    __shared__ float e_lds[S2S_CHUNK];
    __shared__ float red[4];
    __shared__ float rpart[4][64];

    int b = blockIdx.x, tid = threadIdx.x;
    int lane = tid & 63, wv = tid >> 6;
    int s = bstart[b], eend = bstart[b + 1];
    int cntb = eend - s;

    if (tid < 128) qs[tid] = 0.f;
    if (tid < 64) { hs2[tid] = 0.f; cs[tid] = 0.f; }
    __syncthreads();

    for (int step = 0; step < 3; ++step) {
        {
            int u = tid;
            float acc = bil[u] + bhl[u];
            const float4* wi = (const float4*)(Wil + (size_t)u * 128);
#pragma unroll
            for (int k4 = 0; k4 < 32; ++k4) {
                float4 w = wi[k4];
                acc += qs[k4 * 4 + 0] * w.x + qs[k4 * 4 + 1] * w.y +
                       qs[k4 * 4 + 2] * w.z + qs[k4 * 4 + 3] * w.w;
            }
            const float4* wh = (const float4*)(Whl + (size_t)u * 64);
#pragma unroll
            for (int k4 = 0; k4 < 16; ++k4) {
                float4 w = wh[k4];
                acc += hs2[k4 * 4 + 0] * w.x + hs2[k4 * 4 + 1] * w.y +
                       hs2[k4 * 4 + 2] * w.z + hs2[k4 * 4 + 3] * w.w;
            }
            g_lds[u] = acc;
        }
        __syncthreads();
        if (tid < 64) {   // torch order i,f,g,o
            float c = sigmoidf_(g_lds[64 + tid]) * cs[tid] +
                      sigmoidf_(g_lds[tid]) * tanhf(g_lds[128 + tid]);
            cs[tid] = c;
            float h = sigmoidf_(g_lds[192 + tid]) * tanhf(c);
            hs2[tid] = h;
            qs[tid] = h;   // q = hl
        }
        __syncthreads();

        // attention: chunked two-pass softmax, node-parallel
        float gmax = -INFINITY, gsum = 0.f, racc = 0.f;
        for (int c0 = s; c0 < eend; c0 += S2S_CHUNK) {
            int clen = min(S2S_CHUNK, eend - c0);
            for (int i = tid; i < clen; i += 256) {
                const float4* orow = (const float4*)(out + (size_t)(c0 + i) * 64);
                float a0 = 0.f, a1 = 0.f, a2 = 0.f, a3 = 0.f;
#pragma unroll
                for (int k4 = 0; k4 < 16; k4 += 4) {
                    float4 o0 = orow[k4], o1 = orow[k4 + 1], o2 = orow[k4 + 2], o3 = orow[k4 + 3];
                    a0 += o0.x * qs[k4 * 4 + 0]  + o0.y * qs[k4 * 4 + 1]  + o0.z * qs[k4 * 4 + 2]  + o0.w * qs[k4 * 4 + 3];
                    a1 += o1.x * qs[k4 * 4 + 4]  + o1.y * qs[k4 * 4 + 5]  + o1.z * qs[k4 * 4 + 6]  + o1.w * qs[k4 * 4 + 7];
                    a2 += o2.x * qs[k4 * 4 + 8]  + o2.y * qs[k4 * 4 + 9]  + o2.z * qs[k4 * 4 + 10] + o2.w * qs[k4 * 4 + 11];
                    a3 += o3.x * qs[k4 * 4 + 12] + o3.y * qs[k4 * 4 + 13] + o3.z * qs[k4 * 4 + 14] + o3.w * qs[k4 * 4 + 15];
                }
                e_lds[i] = (a0 + a1) + (a2 + a3);
            }
            __syncthreads();
            float m = -INFINITY;
            for (int i = tid; i < clen; i += 256) m = fmaxf(m, e_lds[i]);
            float cmax = block_reduce_max_(m, red, tid);
            float nm = fmaxf(gmax, cmax);
            float scale = expf(gmax - nm);   // 0 on first chunk (gmax=-inf)
            gsum *= scale; racc *= scale;
            float lsum = 0.f;
            for (int i = tid; i < clen; i += 256) {
                float av = expf(e_lds[i] - nm);
                e_lds[i] = av;
                lsum += av;
            }
            gsum += block_reduce_sum_(lsum, red, tid);
            for (int i = wv; i < clen; i += 4)
                racc += e_lds[i] * out[(size_t)(c0 + i) * 64 + lane];
            gmax = nm;
            __syncthreads();
        }
        rpart[wv][lane] = racc;
        __syncthreads();
        if (tid < 64) {
            float r = (rpart[0][tid] + rpart[1][tid]) + (rpart[2][tid] + rpart[3][tid]);
            qs[64 + tid] = (cntb > 0) ? r / gsum : 0.f;
        }
        __syncthreads();
    }

    // final MLP (wave 0)
    if (tid < 64) {
        float acc = bo1[tid];
        const float4* w = (const float4*)(Wo1 + (size_t)tid * 128);
#pragma unroll
        for (int k4 = 0; k4 < 32; ++k4) {
            float4 wv4 = w[k4];
            acc += qs[k4 * 4 + 0] * wv4.x + qs[k4 * 4 + 1] * wv4.y +
                   qs[k4 * 4 + 2] * wv4.z + qs[k4 * 4 + 3] * wv4.w;
        }
        acc = fmaxf(acc, 0.f);
        float t = acc * Wo2[tid];
#pragma unroll
        for (int o = 32; o; o >>= 1) t += __shfl_xor(t, o, 64);
        if (tid == 0) outp[b] = t + bo2[0];
    }
}

extern "C" void kernel_launch(void* const* d_in, const int* in_sizes, int n_in,
                              void* d_out, int out_size, void* d_ws, size_t ws_size,
                              hipStream_t stream) {
    const float* x        = (const float*)d_in[0];
    const float* ea       = (const float*)d_in[1];
    const float* W_in     = (const float*)d_in[2];
    const float* b_in     = (const float*)d_in[3];
    const float* W_e1     = (const float*)d_in[4];
    const float* b_e1     = (const float*)d_in[5];
    const float* W_e2     = (const float*)d_in[6];
    const float* b_e2     = (const float*)d_in[7];
    const float* b_conv   = (const float*)d_in[8];
    const float* W_ih     = (const float*)d_in[9];
    const float* b_ih     = (const float*)d_in[10];
    const float* W_hh     = (const float*)d_in[11];
    const float* b_hh     = (const float*)d_in[12];
    const float* W_ih_l   = (const float*)d_in[13];
    const float* b_ih_l   = (const float*)d_in[14];
    const float* W_hh_l   = (const float*)d_in[15];
    const float* b_hh_l   = (const float*)d_in[16];
    const float* W_o1     = (const float*)d_in[17];
    const float* b_o1     = (const float*)d_in[18];
    const float* W_o2     = (const float*)d_in[19];
    const float* b_o2     = (const float*)d_in[20];
    const int*   ei       = (const int*)d_in[21];
    const int*   batch    = (const int*)d_in[22];
    float* outp = (float*)d_out;

    char* base = (char*)d_ws;
    size_t off = 0;
    auto carve = [&](size_t bytes) -> void* {
        void* p = base + off;
        off = (off + bytes + 255) & ~(size_t)255;
        return p;
    };
    float* out    = (float*)carve((size_t)Nn * 64 * 4);
    float* agg    = (float*)carve((size_t)Nn * 64 * 4);
    float* eh     = (float*)carve((size_t)Ee * 64 * 4);
    unsigned short* Bfat = (unsigned short*)carve((size_t)KSTEPS * 4096 * 2);
    unsigned short* Wg   = (unsigned short*)carve((size_t)4 * 2 * 16 * 64 * 8 * 2);
    float* cnt    = (float*)carve((size_t)Nn * 4);
    int*   bcount = (int*)carve((size_t)Bb * 4);
    int*   bstart = (int*)carve((size_t)(Bb + 1) * 4);
    if (off > ws_size) return;

    hipMemsetAsync(cnt, 0, (size_t)Nn * 4, stream);
    hipMemsetAsync(bcount, 0, (size_t)Bb * 4, stream);

    k_in_linear<<<(Nn * 64) / 256, 256, 0, stream>>>(x, W_in, b_in, out);
    k_edge_mlp1<<<(Ee * 64) / 256, 256, 0, stream>>>(ea, W_e1, b_e1, eh);
    k_make_Bfat<<<(KSTEPS * 4096) / 256, 256, 0, stream>>>(W_e2, b_e2, Bfat);
    k_make_Wg<<<(4 * 2 * 16 * 64 * 8) / 256, 256, 0, stream>>>(W_ih, W_hh, Wg);
    k_count_deg<<<(Ee + 255) / 256, 256, 0, stream>>>(ei, cnt);
    k_count_batch<<<(Nn + 255) / 256, 256, 0, stream>>>(batch, bcount);
    k_scan_batch<<<1, 64, 0, stream>>>(bcount, bstart);

    int eblocks = (Ee + 127) / 128;   // 157
    int nblocks = (Nn + 63) / 64;     // 157
    for (int it = 0; it < 3; ++it) {
        hipMemsetAsync(agg, 0, (size_t)Nn * 64 * 4, stream);
        k_msg_mfma<<<dim3(eblocks, 4), 256, 0, stream>>>(out, eh, Bfat, ei, agg);
        k_gru_mfma<<<nblocks, 256, 0, stream>>>(agg, cnt, b_conv, Wg, b_ih, b_hh, out);
    }

    k_set2set<<<Bb, 256, 0, stream>>>(out, bstart, W_ih_l, b_ih_l, W_hh_l, b_hh_l,
                                      W_o1, b_o1, W_o2, b_o2, outp);
}

// Round 5
// 332.929 us; speedup vs baseline: 1.7785x; 1.0089x over previous
//
#include <hip/hip_runtime.h>
#include <math.h>

// MPNN forward. Round 10:
//  - k_msg_mfma: register-resident A + direct-L2 B, ZERO in-loop barriers.
//    R9 decomposition: 50% of cycles were the LDS pipe (per-ks B re-reads:
//    8x ds_read_b128 x 12 waves/CU x 33 ks) + 66 barrier pairs. Now: each
//    lane's A-operand = 16 floats (cols g*8..+7 / 32+g*8..+7 of its 2 edge
//    rows) held in 32 VGPRs, loaded once; B fragments loaded per-ks directly
//    global->VGPR (L2-resident 1MB table; loads pipeline under MFMA, no
//    sync). Even/odd pair-unrolled ks loop keeps A-reg indexing static.
//    LDS 51.2KB -> 11.3KB (ehs window + srcs/dsts only).
//  - Round 9: 128 edges/block, B-panel amortization. Round 7: compact ehs
//    q-window. Round 6: k_set2set 256-thr node-parallel softmax, shfl scan.
//  - Rounds 1-5: K-split edge MFMA, fused GRU MFMA, split-bf16 hi/lo MFMA
//    (3-term, validated), Bfat/Wg weight pre-pack.

#define Nn 10000
#define Ee 20000
#define Bb 400
#define KSTEPS 130   // 128 (q,d) steps + 2 bias steps (K = 4160)
#define S2S_CHUNK 1024

typedef __attribute__((ext_vector_type(8))) short bf16x8_t;
typedef __attribute__((ext_vector_type(4))) float f32x4_t;

__device__ __forceinline__ float sigmoidf_(float x) { return 1.f / (1.f + expf(-x)); }

// split 8 fp32 -> hi/lo bf16x8 fragments (validated round 4, absmax 0.0)
__device__ __forceinline__ void split8(const float* p, bf16x8_t& Ahi_, bf16x8_t& Alo_) {
    union { bf16x8_t v; unsigned u[4]; } hi, lo;
#pragma unroll
    for (int ii = 0; ii < 4; ++ii) {
        float pa = p[2 * ii], pb = p[2 * ii + 1];
        unsigned ua = __float_as_uint(pa), ub = __float_as_uint(pb);
        hi.u[ii] = (ua >> 16) | (ub & 0xFFFF0000u);
        float la = pa - __uint_as_float(ua & 0xFFFF0000u);
        float lb = pb - __uint_as_float(ub & 0xFFFF0000u);
        lo.u[ii] = (__float_as_uint(la) >> 16) | (__float_as_uint(lb) & 0xFFFF0000u);
    }
    Ahi_ = hi.v; Alo_ = lo.v;
}

__global__ __launch_bounds__(256) void k_in_linear(const float* __restrict__ x,
                                                   const float* __restrict__ Win,
                                                   const float* __restrict__ bin,
                                                   float* __restrict__ out) {
    int idx = blockIdx.x * 256 + threadIdx.x;
    if (idx >= Nn * 64) return;
    int n = idx >> 6, j = idx & 63;
    const float* xr = x + n * 32;
    const float* w = Win + j * 32;
    float acc = bin[j];
#pragma unroll
    for (int k = 0; k < 32; ++k) acc += xr[k] * w[k];
    out[idx] = fmaxf(acc, 0.f);
}

__global__ __launch_bounds__(256) void k_edge_mlp1(const float* __restrict__ ea,
                                                   const float* __restrict__ W1,
                                                   const float* __restrict__ b1,
                                                   float* __restrict__ eh) {
    int idx = blockIdx.x * 256 + threadIdx.x;
    if (idx >= Ee * 64) return;
    int e = idx >> 6, j = idx & 63;
    const float* ar = ea + e * 16;
    const float* w = W1 + j * 16;
    float acc = b1[j];
#pragma unroll
    for (int k = 0; k < 16; ++k) acc += ar[k] * w[k];
    eh[idx] = fmaxf(acc, 0.f);
}

// Bfat[kstep][h][nq][lane][i] (bf16), as round 4 (validated).
__global__ __launch_bounds__(256) void k_make_Bfat(const float* __restrict__ W2,
                                                   const float* __restrict__ b2,
                                                   unsigned short* __restrict__ Bfat) {
    int idx = blockIdx.x * 256 + threadIdx.x;
    if (idx >= KSTEPS * 4096) return;
    int i  = idx & 7;
    int l  = (idx >> 3) & 63;
    int nq = (idx >> 9) & 3;
    int h  = (idx >> 11) & 1;
    int ks = idx >> 12;
    int kap = ks * 32 + (l >> 4) * 8 + i;
    int f = nq * 16 + (l & 15);
    float w;
    if (kap < 4096) {
        int q = kap >> 6, d = kap & 63;
        w = W2[(size_t)(d * 64 + f) * 64 + q];
    } else {
        int d = kap - 4096;
        w = b2[d * 64 + f];
    }
    unsigned u = __float_as_uint(w);
    unsigned short outv;
    if (h == 0) {
        outv = (unsigned short)(u >> 16);
    } else {
        float lo = w - __uint_as_float(u & 0xFFFF0000u);
        outv = (unsigned short)(__float_as_uint(lo) >> 16);
    }
    Bfat[idx] = outv;
}

// Wg[ks][h][t][lane][i] (bf16): GRU-gates B table, N=256 cols:
//  t 0-3: i_r+h_r (k<64: W_ih[j][k], k>=64: W_hh[j][k-64])
//  t 4-7: i_z+h_z; t 8-11: i_n only; t 12-15: h_n only.
__global__ __launch_bounds__(256) void k_make_Wg(const float* __restrict__ Wih,
                                                 const float* __restrict__ Whh,
                                                 unsigned short* __restrict__ Wg) {
    int idx = blockIdx.x * 256 + threadIdx.x;
    if (idx >= 4 * 2 * 16 * 64 * 8) return;
    int i  = idx & 7;
    int l  = (idx >> 3) & 63;
    int t  = (idx >> 9) & 15;
    int h  = (idx >> 13) & 1;
    int ks = idx >> 14;
    int k = ks * 32 + (l >> 4) * 8 + i;
    int u = t * 16 + (l & 15);
    int j = u & 63, part = u >> 6;   // 0:r, 1:z, 2:i_n, 3:h_n
    float w = 0.f;
    if (part == 0) w = (k < 64) ? Wih[(size_t)j * 64 + k]          : Whh[(size_t)j * 64 + (k - 64)];
    if (part == 1) w = (k < 64) ? Wih[(size_t)(64 + j) * 64 + k]   : Whh[(size_t)(64 + j) * 64 + (k - 64)];
    if (part == 2) w = (k < 64) ? Wih[(size_t)(128 + j) * 64 + k]  : 0.f;
    if (part == 3) w = (k < 64) ? 0.f : Whh[(size_t)(128 + j) * 64 + (k - 64)];
    unsigned uu = __float_as_uint(w);
    unsigned short outv;
    if (h == 0) {
        outv = (unsigned short)(uu >> 16);
    } else {
        float lo = w - __uint_as_float(uu & 0xFFFF0000u);
        outv = (unsigned short)(__float_as_uint(lo) >> 16);
    }
    Wg[idx] = outv;
}

// Edge-direct message pass, K-split x4 across blockIdx.y, 128 edges/block.
// A in registers (16 floats/lane/tile), B direct global->VGPR per ks.
// No in-loop barriers; only ehs/srcs/dsts in LDS (11.3KB).
__global__ __launch_bounds__(256, 3) void k_msg_mfma(const float* __restrict__ out,
                                                     const float* __restrict__ eh,
                                                     const unsigned short* __restrict__ Bfat,
                                                     const int* __restrict__ ei,
                                                     float* __restrict__ agg) {
    __shared__ float ehs[128][20];   // compact q-window [q0, q0+qn)
    __shared__ int srcs[128];
    __shared__ int dsts[128];
    int tid = threadIdx.x;
    int ebase = blockIdx.x * 128;
    int ksplit = blockIdx.y;

    int ks0 = ksplit * 32 + (ksplit < 2 ? ksplit : 2);      // 0,33,66,98
    int ks1 = ks0 + (ksplit < 2 ? 33 : 32);                 // 33,66,98,130
    int q0 = ks0 >> 1;
    int qn = ((min(ks1, 128) - 1) >> 1) - q0 + 1;           // <= 17

    {   // stage srcs/dsts + ehs window: 2 threads per edge
        int el = tid >> 1, seg = tid & 1;
        int eg = ebase + el;
        bool v = eg < Ee;
        if (seg == 0) {
            srcs[el] = v ? ei[eg] : 0;
            dsts[el] = v ? ei[Ee + eg] : 0;
        }
        const float* erow = eh + (size_t)eg * 64;
        for (int j = seg; j < qn; j += 2)
            ehs[el][j] = v ? erow[q0 + j] : 0.f;
    }
    __syncthreads();

    int lane = tid & 63;
    int wtile = tid >> 6;
    int m16 = lane & 15;
    int g = lane >> 4;
    int erA = wtile * 32 + m16;
    int erB = erA + 16;

    // A registers: per tile, half0 = cols [g*8, g*8+8), half1 = [32+g*8, ...)
    float a0[2][8], a1[2][8];
    {
        const float* rA = out + (size_t)srcs[erA] * 64;
        const float* rB = out + (size_t)srcs[erB] * 64;
        float4 v0, v1;
        v0 = *(const float4*)(rA + g * 8);      v1 = *(const float4*)(rA + g * 8 + 4);
        a0[0][0]=v0.x; a0[0][1]=v0.y; a0[0][2]=v0.z; a0[0][3]=v0.w;
        a0[0][4]=v1.x; a0[0][5]=v1.y; a0[0][6]=v1.z; a0[0][7]=v1.w;
        v0 = *(const float4*)(rA + 32 + g * 8); v1 = *(const float4*)(rA + 36 + g * 8);
        a1[0][0]=v0.x; a1[0][1]=v0.y; a1[0][2]=v0.z; a1[0][3]=v0.w;
        a1[0][4]=v1.x; a1[0][5]=v1.y; a1[0][6]=v1.z; a1[0][7]=v1.w;
        v0 = *(const float4*)(rB + g * 8);      v1 = *(const float4*)(rB + g * 8 + 4);
        a0[1][0]=v0.x; a0[1][1]=v0.y; a0[1][2]=v0.z; a0[1][3]=v0.w;
        a0[1][4]=v1.x; a0[1][5]=v1.y; a0[1][6]=v1.z; a0[1][7]=v1.w;
        v0 = *(const float4*)(rB + 32 + g * 8); v1 = *(const float4*)(rB + 36 + g * 8);
        a1[1][0]=v0.x; a1[1][1]=v0.y; a1[1][2]=v0.z; a1[1][3]=v0.w;
        a1[1][4]=v1.x; a1[1][5]=v1.y; a1[1][6]=v1.z; a1[1][7]=v1.w;
    }

    f32x4_t acc[2][4];
#pragma unroll
    for (int t = 0; t < 2; ++t)
#pragma unroll
        for (int nq = 0; nq < 4; ++nq) acc[t][nq] = (f32x4_t){0.f, 0.f, 0.f, 0.f};

    auto body = [&](int ks, const float (&Av)[2][8], float qA, float qB) {
        const unsigned short* bstep = Bfat + (size_t)ks * 4096;
        bf16x8_t bhi[4], blo[4];
#pragma unroll
        for (int nq = 0; nq < 4; ++nq) {
            bhi[nq] = *(const bf16x8_t*)(bstep + ((size_t)(nq * 64 + lane)) * 8);
            blo[nq] = *(const bf16x8_t*)(bstep + ((size_t)((4 + nq) * 64 + lane)) * 8);
        }
        float pA[8], pB[8];
#pragma unroll
        for (int i = 0; i < 8; ++i) { pA[i] = Av[0][i] * qA; pB[i] = Av[1][i] * qB; }
        bf16x8_t AhiA, AloA, AhiB, AloB;
        split8(pA, AhiA, AloA);
        split8(pB, AhiB, AloB);
#pragma unroll
        for (int nq = 0; nq < 4; ++nq) {
            acc[0][nq] = __builtin_amdgcn_mfma_f32_16x16x32_bf16(AhiA, bhi[nq], acc[0][nq], 0, 0, 0);
            acc[0][nq] = __builtin_amdgcn_mfma_f32_16x16x32_bf16(AhiA, blo[nq], acc[0][nq], 0, 0, 0);
            acc[0][nq] = __builtin_amdgcn_mfma_f32_16x16x32_bf16(AloA, bhi[nq], acc[0][nq], 0, 0, 0);
            acc[1][nq] = __builtin_amdgcn_mfma_f32_16x16x32_bf16(AhiB, bhi[nq], acc[1][nq], 0, 0, 0);
            acc[1][nq] = __builtin_amdgcn_mfma_f32_16x16x32_bf16(AhiB, blo[nq], acc[1][nq], 0, 0, 0);
            acc[1][nq] = __builtin_amdgcn_mfma_f32_16x16x32_bf16(AloB, bhi[nq], acc[1][nq], 0, 0, 0);
        }
    };

    // even/odd pair loop: A-register half selected statically per body
    for (int kp = ks0 & ~1; kp < ks1; kp += 2) {
        float qA = 1.f, qB = 1.f;
        if (kp < 128) {
            int qi = (kp >> 1) - q0;
            qA = ehs[erA][qi];
            qB = ehs[erB][qi];
        }
        if (kp >= ks0)    body(kp,     a0, qA, qB);
        if (kp + 1 < ks1) body(kp + 1, a1, qA, qB);
    }

#pragma unroll
    for (int t = 0; t < 2; ++t) {
#pragma unroll
        for (int r = 0; r < 4; ++r) {
            int el = wtile * 32 + t * 16 + g * 4 + r;
            int eg = ebase + el;
            if (eg >= Ee) continue;
            int dn = dsts[el];
#pragma unroll
            for (int nq = 0; nq < 4; ++nq)
                atomicAdd(&agg[(size_t)dn * 64 + nq * 16 + m16], acc[t][nq][r]);
        }
    }
}

// Fused GRU: stage m = relu(agg/cnt + b_conv) and h = out in LDS; gates via
// split-bf16 MFMA (A=[m|h] K=128, N=256); combine in epilogue; out updated.
__global__ __launch_bounds__(256) void k_gru_mfma(const float* __restrict__ agg,
                                                  const float* __restrict__ cnt,
                                                  const float* __restrict__ bconv,
                                                  const unsigned short* __restrict__ Wg,
                                                  const float* __restrict__ bih,
                                                  const float* __restrict__ bhh,
                                                  float* __restrict__ out) {
    __shared__ float ms[64][68];
    __shared__ float hs[64][68];
    int tid = threadIdx.x;
    int nbase = blockIdx.x * 64;

    {   // stage: 4 threads per node, 16 cols each
        int nl = tid >> 2, seg = tid & 3;
        int ng = nbase + nl;
        bool v = ng < Nn;
        float c = v ? cnt[ng] : 1.f;
        c = c < 1.f ? 1.f : c;
        float rc = 1.f / c;
        const float* arow = agg + (size_t)ng * 64 + seg * 16;
        const float* hrow = out + (size_t)ng * 64 + seg * 16;
#pragma unroll
        for (int c4 = 0; c4 < 4; ++c4) {
            int col = seg * 16 + c4 * 4;
            float4 z = make_float4(0.f, 0.f, 0.f, 0.f);
            float4 av = v ? *(const float4*)(arow + c4 * 4) : z;
            float4 hv = v ? *(const float4*)(hrow + c4 * 4) : z;
            ms[nl][col + 0] = fmaxf(av.x * rc + bconv[col + 0], 0.f);
            ms[nl][col + 1] = fmaxf(av.y * rc + bconv[col + 1], 0.f);
            ms[nl][col + 2] = fmaxf(av.z * rc + bconv[col + 2], 0.f);
            ms[nl][col + 3] = fmaxf(av.w * rc + bconv[col + 3], 0.f);
            *(float4*)&hs[nl][col] = hv;
        }
    }
    __syncthreads();

    int lane = tid & 63;
    int wtile = tid >> 6;
    int m16 = lane & 15;
    int g = lane >> 4;
    int er = wtile * 16 + m16;

    f32x4_t acc[16];
#pragma unroll
    for (int t = 0; t < 16; ++t) acc[t] = (f32x4_t){0.f, 0.f, 0.f, 0.f};

#pragma unroll
    for (int ks = 0; ks < 4; ++ks) {
        const float* src = (ks < 2) ? &ms[er][ks * 32 + g * 8]
                                    : &hs[er][(ks - 2) * 32 + g * 8];
        float p[8];
#pragma unroll
        for (int ii = 0; ii < 8; ++ii) p[ii] = src[ii];
        bf16x8_t Ahi, Alo;
        split8(p, Ahi, Alo);
        const unsigned short* bstep = Wg + (size_t)ks * (2 * 16 * 512);
#pragma unroll
        for (int t = 0; t < 16; ++t) {
            bf16x8_t bhi = *(const bf16x8_t*)(bstep + ((size_t)t * 64 + lane) * 8);
            bf16x8_t blo = *(const bf16x8_t*)(bstep + ((size_t)(16 + t) * 64 + lane) * 8);
            acc[t] = __builtin_amdgcn_mfma_f32_16x16x32_bf16(Ahi, bhi, acc[t], 0, 0, 0);
            acc[t] = __builtin_amdgcn_mfma_f32_16x16x32_bf16(Ahi, blo, acc[t], 0, 0, 0);
            acc[t] = __builtin_amdgcn_mfma_f32_16x16x32_bf16(Alo, bhi, acc[t], 0, 0, 0);
        }
    }

    // epilogue: GRU combine, fully lane-local
#pragma unroll
    for (int t2 = 0; t2 < 4; ++t2) {
        int jj = t2 * 16 + m16;
        float br = bih[jj] + bhh[jj];
        float bz = bih[64 + jj] + bhh[64 + jj];
        float bin_ = bih[128 + jj];
        float bhn = bhh[128 + jj];
#pragma unroll
        for (int r = 0; r < 4; ++r) {
            int nl2 = wtile * 16 + g * 4 + r;
            int ng2 = nbase + nl2;
            if (ng2 >= Nn) continue;
            float rg = sigmoidf_(acc[t2][r] + br);
            float z  = sigmoidf_(acc[4 + t2][r] + bz);
            float nn = tanhf(acc[8 + t2][r] + bin_ + rg * (acc[12 + t2][r] + bhn));
            float hv = hs[nl2][jj];
            out[(size_t)ng2 * 64 + jj] = (1.f - z) * nn + z * hv;
        }
    }
}

__global__ __launch_bounds__(256) void k_count_deg(const int* __restrict__ ei,
                                                   float* __restrict__ cnt) {
    int e = blockIdx.x * 256 + threadIdx.x;
    if (e >= Ee) return;
    atomicAdd(&cnt[ei[Ee + e]], 1.f);
}

__global__ __launch_bounds__(256) void k_count_batch(const int* __restrict__ batch,
                                                     int* __restrict__ bcount) {
    int n = blockIdx.x * 256 + threadIdx.x;
    if (n >= Nn) return;
    atomicAdd(&bcount[batch[n]], 1);
}

// One-wave parallel exclusive scan over Bb=400 counts.
__global__ __launch_bounds__(64) void k_scan_batch(const int* __restrict__ bcount,
                                                   int* __restrict__ bstart) {
    int lane = threadIdx.x;
    const int PER = (Bb + 63) / 64;   // 7
    int base = lane * PER;
    int v[PER];
    int s = 0;
#pragma unroll
    for (int i = 0; i < PER; ++i) {
        int idx = base + i;
        int c = (idx < Bb) ? bcount[idx] : 0;
        v[i] = s;
        s += c;
    }
    int inc = s;
#pragma unroll
    for (int o = 1; o < 64; o <<= 1) {
        int t = __shfl_up(inc, o, 64);
        if (lane >= o) inc += t;
    }
    int excl = inc - s;
    int total = __shfl(inc, 63, 64);
#pragma unroll
    for (int i = 0; i < PER; ++i) {
        int idx = base + i;
        if (idx < Bb) bstart[idx] = excl + v[i];
    }
    if (lane == 63) bstart[Bb] = total;
}

// Block-wide reductions (uniform result broadcast to all 256 threads).
__device__ __forceinline__ float block_reduce_max_(float v, float* red, int tid) {
#pragma unroll
    for (int o = 32; o; o >>= 1) v = fmaxf(v, __shfl_xor(v, o, 64));
    if ((tid & 63) == 0) red[tid >> 6] = v;
    __syncthreads();
    float r = fmaxf(fmaxf(red[0], red[1]), fmaxf(red[2], red[3]));
    __syncthreads();
    return r;
}
__device__ __forceinline__ float block_reduce_sum_(float v, float* red, int tid) {
#pragma unroll
    for (int o = 32; o; o >>= 1) v += __shfl_xor(v, o, 64);
    if ((tid & 63) == 0) red[tid >> 6] = v;
    __syncthreads();
    float r = (red[0] + red[1]) + (red[2] + red[3]);
    __syncthreads();
    return r;
}

// Fused Set2Set: one 256-thread block per graph (round 6, validated).
__global__ __launch_bounds__(256) void k_set2set(const float* __restrict__ out,
                                                 const int* __restrict__ bstart,
                                                 const float* __restrict__ Wil,
                                                 const float* __restrict__ bil,
                                                 const float* __restrict__ Whl,
                                                 const float* __restrict__ bhl,
                                                 const float* __restrict__ Wo1,
                                                 const float* __restrict__ bo1,
                                                 const float* __restrict__ Wo2,
                                                 const float* __restrict__ bo2,
                                                 float* __restrict__ outp) {
    __shared__ float qs[128];        // q_star = [q | r]
    __shared__ float hs2[64];        // hl
    __shared__ float cs[64];         // cl
    __shared__ float g_lds[256];     // LSTM gates
    __shared__ float e_lds[S2S_CHUNK];
    __shared__ float red[4];
    __shared__ float rpart[4][64];

    int b = blockIdx.x, tid = threadIdx.x;
    int lane = tid & 63, wv = tid >> 6;
    int s = bstart[b], eend = bstart[b + 1];
    int cntb = eend - s;

    if (tid < 128) qs[tid] = 0.f;
    if (tid < 64) { hs2[tid] = 0.f; cs[tid] = 0.f; }
    __syncthreads();

    for (int step = 0; step < 3; ++step) {
        {
            int u = tid;
            float acc = bil[u] + bhl[u];
            const float4* wi = (const float4*)(Wil + (size_t)u * 128);
#pragma unroll
            for (int k4 = 0; k4 < 32; ++k4) {
                float4 w = wi[k4];
                acc += qs[k4 * 4 + 0] * w.x + qs[k4 * 4 + 1] * w.y +
                       qs[k4 * 4 + 2] * w.z + qs[k4 * 4 + 3] * w.w;
            }
            const float4* wh = (const float4*)(Whl + (size_t)u * 64);
#pragma unroll
            for (int k4 = 0; k4 < 16; ++k4) {
                float4 w = wh[k4];
                acc += hs2[k4 * 4 + 0] * w.x + hs2[k4 * 4 + 1] * w.y +
                       hs2[k4 * 4 + 2] * w.z + hs2[k4 * 4 + 3] * w.w;
            }
            g_lds[u] = acc;
        }
        __syncthreads();
        if (tid < 64) {   // torch order i,f,g,o
            float c = sigmoidf_(g_lds[64 + tid]) * cs[tid] +
                      sigmoidf_(g_lds[tid]) * tanhf(g_lds[128 + tid]);
            cs[tid] = c;
            float h = sigmoidf_(g_lds[192 + tid]) * tanhf(c);
            hs2[tid] = h;
            qs[tid] = h;   // q = hl
        }
        __syncthreads();

        // attention: chunked two-pass softmax, node-parallel
        float gmax = -INFINITY, gsum = 0.f, racc = 0.f;
        for (int c0 = s; c0 < eend; c0 += S2S_CHUNK) {
            int clen = min(S2S_CHUNK, eend - c0);
            for (int i = tid; i < clen; i += 256) {
                const float4* orow = (const float4*)(out + (size_t)(c0 + i) * 64);
                float a0 = 0.f, a1 = 0.f, a2 = 0.f, a3 = 0.f;
#pragma unroll
                for (int k4 = 0; k4 < 16; k4 += 4) {
                    float4 o0 = orow[k4], o1 = orow[k4 + 1], o2 = orow[k4 + 2], o3 = orow[k4 + 3];
                    a0 += o0.x * qs[k4 * 4 + 0]  + o0.y * qs[k4 * 4 + 1]  + o0.z * qs[k4 * 4 + 2]  + o0.w * qs[k4 * 4 + 3];
                    a1 += o1.x * qs[k4 * 4 + 4]  + o1.y * qs[k4 * 4 + 5]  + o1.z * qs[k4 * 4 + 6]  + o1.w * qs[k4 * 4 + 7];
                    a2 += o2.x * qs[k4 * 4 + 8]  + o2.y * qs[k4 * 4 + 9]  + o2.z * qs[k4 * 4 + 10] + o2.w * qs[k4 * 4 + 11];
                    a3 += o3.x * qs[k4 * 4 + 12] + o3.y * qs[k4 * 4 + 13] + o3.z * qs[k4 * 4 + 14] + o3.w * qs[k4 * 4 + 15];
                }
                e_lds[i] = (a0 + a1) + (a2 + a3);
            }
            __syncthreads();
            float m = -INFINITY;
            for (int i = tid; i < clen; i += 256) m = fmaxf(m, e_lds[i]);
            float cmax = block_reduce_max_(m, red, tid);
            float nm = fmaxf(gmax, cmax);
            float scale = expf(gmax - nm);   // 0 on first chunk (gmax=-inf)
            gsum *= scale; racc *= scale;
            float lsum = 0.f;
            for (int i = tid; i < clen; i += 256) {
                float av = expf(e_lds[i] - nm);
                e_lds[i] = av;
                lsum += av;
            }
            gsum += block_reduce_sum_(lsum, red, tid);
            for (int i = wv; i < clen; i += 4)
                racc += e_lds[i] * out[(size_t)(c0 + i) * 64 + lane];
            gmax = nm;
            __syncthreads();
        }
        rpart[wv][lane] = racc;
        __syncthreads();
        if (tid < 64) {
            float r = (rpart[0][tid] + rpart[1][tid]) + (rpart[2][tid] + rpart[3][tid]);
            qs[64 + tid] = (cntb > 0) ? r / gsum : 0.f;
        }
        __syncthreads();
    }

    // final MLP (wave 0)
    if (tid < 64) {
        float acc = bo1[tid];
        const float4* w = (const float4*)(Wo1 + (size_t)tid * 128);
#pragma unroll
        for (int k4 = 0; k4 < 32; ++k4) {
            float4 wv4 = w[k4];
            acc += qs[k4 * 4 + 0] * wv4.x + qs[k4 * 4 + 1] * wv4.y +
                   qs[k4 * 4 + 2] * wv4.z + qs[k4 * 4 + 3] * wv4.w;
        }
        acc = fmaxf(acc, 0.f);
        float t = acc * Wo2[tid];
#pragma unroll
        for (int o = 32; o; o >>= 1) t += __shfl_xor(t, o, 64);
        if (tid == 0) outp[b] = t + bo2[0];
    }
}

extern "C" void kernel_launch(void* const* d_in, const int* in_sizes, int n_in,
                              void* d_out, int out_size, void* d_ws, size_t ws_size,
                              hipStream_t stream) {
    const float* x        = (const float*)d_in[0];
    const float* ea       = (const float*)d_in[1];
    const float* W_in     = (const float*)d_in[2];
    const float* b_in     = (const float*)d_in[3];
    const float* W_e1     = (const float*)d_in[4];
    const float* b_e1     = (const float*)d_in[5];
    const float* W_e2     = (const float*)d_in[6];
    const float* b_e2     = (const float*)d_in[7];
    const float* b_conv   = (const float*)d_in[8];
    const float* W_ih     = (const float*)d_in[9];
    const float* b_ih     = (const float*)d_in[10];
    const float* W_hh     = (const float*)d_in[11];
    const float* b_hh     = (const float*)d_in[12];
    const float* W_ih_l   = (const float*)d_in[13];
    const float* b_ih_l   = (const float*)d_in[14];
    const float* W_hh_l   = (const float*)d_in[15];
    const float* b_hh_l   = (const float*)d_in[16];
    const float* W_o1     = (const float*)d_in[17];
    const float* b_o1     = (const float*)d_in[18];
    const float* W_o2     = (const float*)d_in[19];
    const float* b_o2     = (const float*)d_in[20];
    const int*   ei       = (const int*)d_in[21];
    const int*   batch    = (const int*)d_in[22];
    float* outp = (float*)d_out;

    char* base = (char*)d_ws;
    size_t off = 0;
    auto carve = [&](size_t bytes) -> void* {
        void* p = base + off;
        off = (off + bytes + 255) & ~(size_t)255;
        return p;
    };
    float* out    = (float*)carve((size_t)Nn * 64 * 4);
    float* agg    = (float*)carve((size_t)Nn * 64 * 4);
    float* eh     = (float*)carve((size_t)Ee * 64 * 4);
    unsigned short* Bfat = (unsigned short*)carve((size_t)KSTEPS * 4096 * 2);
    unsigned short* Wg   = (unsigned short*)carve((size_t)4 * 2 * 16 * 64 * 8 * 2);
    float* cnt    = (float*)carve((size_t)Nn * 4);
    int*   bcount = (int*)carve((size_t)Bb * 4);
    int*   bstart = (int*)carve((size_t)(Bb + 1) * 4);
    if (off > ws_size) return;

    hipMemsetAsync(cnt, 0, (size_t)Nn * 4, stream);
    hipMemsetAsync(bcount, 0, (size_t)Bb * 4, stream);

    k_in_linear<<<(Nn * 64) / 256, 256, 0, stream>>>(x, W_in, b_in, out);
    k_edge_mlp1<<<(Ee * 64) / 256, 256, 0, stream>>>(ea, W_e1, b_e1, eh);
    k_make_Bfat<<<(KSTEPS * 4096) / 256, 256, 0, stream>>>(W_e2, b_e2, Bfat);
    k_make_Wg<<<(4 * 2 * 16 * 64 * 8) / 256, 256, 0, stream>>>(W_ih, W_hh, Wg);
    k_count_deg<<<(Ee + 255) / 256, 256, 0, stream>>>(ei, cnt);
    k_count_batch<<<(Nn + 255) / 256, 256, 0, stream>>>(batch, bcount);
    k_scan_batch<<<1, 64, 0, stream>>>(bcount, bstart);

    int eblocks = (Ee + 127) / 128;   // 157
    int nblocks = (Nn + 63) / 64;     // 157
    for (int it = 0; it < 3; ++it) {
        hipMemsetAsync(agg, 0, (size_t)Nn * 64 * 4, stream);
        k_msg_mfma<<<dim3(eblocks, 4), 256, 0, stream>>>(out, eh, Bfat, ei, agg);
        k_gru_mfma<<<nblocks, 256, 0, stream>>>(agg, cnt, b_conv, Wg, b_ih, b_hh, out);
    }

    k_set2set<<<Bb, 256, 0, stream>>>(out, bstart, W_ih_l, b_ih_l, W_hh_l, b_hh_l,
                                      W_o1, b_o1, W_o2, b_o2, outp);
}